// Round 2
// baseline (51.144 us; speedup 1.0000x reference)
//
#include <hip/hip_runtime.h>

// ContrastLoss: B=2, M=2048, T=4096, K=16, DT=150
// Band bins of rfft(150) kept by mask: k = 4..20 (17 bins).
// Mean-subtract & /delta_t cancel for these bins -> raw Goertzel powers, normalized.
// Loss = closed form over sumsq(psd^2) and per-video column sums (17 each).

#define T_LEN 4096
#define M_ROWS 2048
#define KSEG 16
#define NROWS 4096      // B*M
#define DTLEN 150
#define NBIN 17
#define BIN0 4

// ---------------- Kernel 1: per-row PSD partials ----------------
// grid = 4096 blocks, block = 64 threads (1 wave per (b,m) row).
// Each lane: seg = lane>>2 (16 segs), grp = lane&3 (bin groups 5/4/4/4).
// Writes ws[row*18 + 0] = sum of normalized psd^2 over row's 16 segs,
//        ws[row*18 + 1 + f] = column sum over segs of normalized psd[f].
__global__ __launch_bounds__(64) void psd_partials(const float* __restrict__ mo,
                                                   const int* __restrict__ offs,
                                                   float* __restrict__ ws) {
  __shared__ float row[T_LEN];
  __shared__ float psd[KSEG][NBIN];
  __shared__ float rcp[KSEG];
  __shared__ float ssp[NBIN];

  const int r = blockIdx.x;
  const int t = threadIdx.x;

  // stage full row (16 KB) into LDS, coalesced float4
  {
    const float4* src = (const float4*)(mo + (size_t)r * T_LEN);
    float4* dst = (float4*)row;
    #pragma unroll
    for (int i = 0; i < T_LEN / 4 / 64; ++i) dst[t + 64 * i] = src[t + 64 * i];
  }
  __syncthreads();

  const int seg = t >> 2;
  const int g = t & 3;
  const int off = offs[r * KSEG + seg];
  // bin groups: g0 -> 4..8 (5 bins), g1 -> 9..12, g2 -> 13..16, g3 -> 17..20
  const int b0 = (g == 0) ? 4 : (5 + 4 * g);
  const int nb = (g == 0) ? 5 : 4;

  float c[5], s1[5], s2[5];
  #pragma unroll
  for (int j = 0; j < 5; ++j) {
    // c = 2*cos(2*pi*k/150); dummy 5th bin (c=0) for 4-bin lanes keeps lanes uniform
    double k = (double)(b0 + j);
    c[j] = (j < nb) ? (float)(2.0 * cos(6.283185307179586476925286766559 * k / 150.0)) : 0.0f;
    s1[j] = 0.0f;
    s2[j] = 0.0f;
  }

  const float* __restrict__ x = row + off;
  // Goertzel, 2 samples per step (150 even), 5 bins per lane
  #pragma unroll 3
  for (int n = 0; n < DTLEN; n += 2) {
    float x0 = x[n];
    float x1 = x[n + 1];
    #pragma unroll
    for (int j = 0; j < 5; ++j) {
      s2[j] = fmaf(c[j], s1[j], x0 - s2[j]);
      s1[j] = fmaf(c[j], s2[j], x1 - s1[j]);
    }
  }
  #pragma unroll
  for (int j = 0; j < 5; ++j) {
    if (j < nb) {
      // |X_k|^2 = s1^2 + s2^2 - 2cos(w) s1 s2
      float p = fmaf(s1[j], s1[j], s2[j] * s2[j]) - c[j] * s1[j] * s2[j];
      psd[seg][b0 - BIN0 + j] = p;
    }
  }
  __syncthreads();

  // per-seg band sum -> reciprocal
  if (t < KSEG) {
    float s = 0.0f;
    #pragma unroll
    for (int f = 0; f < NBIN; ++f) s += psd[t][f];
    rcp[t] = 1.0f / s;
  }
  __syncthreads();

  // column sums + per-bin sumsq of normalized psd
  if (t < NBIN) {
    float col = 0.0f, ss = 0.0f;
    #pragma unroll
    for (int s = 0; s < KSEG; ++s) {
      float p = psd[s][t] * rcp[s];
      col += p;
      ss = fmaf(p, p, ss);
    }
    ws[r * 18 + 1 + t] = col;
    ssp[t] = ss;
  }
  __syncthreads();

  if (t == 0) {
    float s = 0.0f;
    #pragma unroll
    for (int f = 0; f < NBIN; ++f) s += ssp[f];
    ws[r * 18] = s;
  }
}

// ---------------- Kernel 2: final reduction (1 block) ----------------
__global__ __launch_bounds__(1024) void final_reduce(const float* __restrict__ ws,
                                                     float* __restrict__ out) {
  const int t = threadIdx.x;
  double accA[18], accB[18];
  #pragma unroll
  for (int i = 0; i < 18; ++i) { accA[i] = 0.0; accB[i] = 0.0; }

  // rows t, t+1024 are video A (0..2047); rows t+2048, t+3072 are video B
  #pragma unroll
  for (int h = 0; h < 2; ++h) {
    const float* p = ws + (t + 1024 * h) * 18;
    #pragma unroll
    for (int e = 0; e < 18; ++e) accA[e] += (double)p[e];
  }
  #pragma unroll
  for (int h = 2; h < 4; ++h) {
    const float* p = ws + (t + 1024 * h) * 18;
    #pragma unroll
    for (int e = 0; e < 18; ++e) accB[e] += (double)p[e];
  }

  // wave butterfly reduce (64 lanes)
  #pragma unroll
  for (int off = 32; off >= 1; off >>= 1) {
    #pragma unroll
    for (int i = 0; i < 18; ++i) {
      accA[i] += __shfl_down(accA[i], off, 64);
      accB[i] += __shfl_down(accB[i], off, 64);
    }
  }

  __shared__ double wsum[16][36];
  const int wid = t >> 6, lane = t & 63;
  if (lane == 0) {
    #pragma unroll
    for (int i = 0; i < 18; ++i) { wsum[wid][i] = accA[i]; wsum[wid][18 + i] = accB[i]; }
  }
  __syncthreads();

  __shared__ double fin[36];
  if (t < 36) {
    double s = 0.0;
    #pragma unroll
    for (int w = 0; w < 16; ++w) s += wsum[w][t];
    fin[t] = s;
  }
  __syncthreads();

  if (t == 0) {
    double sumA2 = fin[0], sumB2 = fin[18];
    double dAA = 0.0, dBB = 0.0, dAB = 0.0;
    for (int f = 0; f < NBIN; ++f) {
      double ca = fin[1 + f], cb = fin[19 + f];
      dAA += ca * ca;
      dBB += cb * cb;
      dAB += ca * cb;
    }
    const double N = 32768.0, Fb = 17.0;
    double pAA = (2.0 * N * sumA2 - 2.0 * dAA) / Fb;
    double pBB = (2.0 * N * sumB2 - 2.0 * dBB) / Fb;
    double pAB = (N * sumA2 + N * sumB2 - 2.0 * dAB) / Fb;
    double selfa = pAA / (N * (N - 1.0));
    double selfb = pBB / (N * (N - 1.0));
    double res = 0.5 * (selfa + selfb) + pAB / (N * N);
    out[0] = (float)res;
  }
}

extern "C" void kernel_launch(void* const* d_in, const int* in_sizes, int n_in,
                              void* d_out, int out_size, void* d_ws, size_t ws_size,
                              hipStream_t stream) {
  const float* mo = (const float*)d_in[0];   // (2, 2048, 4096) f32
  const int* offs = (const int*)d_in[1];     // (2, 2048, 16) i32
  // d_in[2] = delta_t (=150), compile-time constant here
  float* out = (float*)d_out;
  float* ws = (float*)d_ws;                  // needs 4096*18*4 = 294912 B

  psd_partials<<<NROWS, 64, 0, stream>>>(mo, offs, ws);
  final_reduce<<<1, 1024, 0, stream>>>(ws, out);
}

// Round 3
// 43.641 us; speedup vs baseline: 1.1719x; 1.1719x over previous
//
#include <hip/hip_runtime.h>
#include <stdint.h>

// ContrastLoss: B=2, M=2048, T=4096, K=16, DT=150
// Band bins of rfft(150) kept: k = 4..20 (17 bins). Mean-subtract & /dt cancel.
// Per-segment Goertzel -> normalized PSD -> closed-form loss from moments.

#define T_LEN 4096
#define KSEG 16
#define NROWS 4096      // B*M
#define DTLEN 150
#define NBIN 17
#define SEG_STRIDE 154  // floats; banks (154*s+n)%32 = (26s+n)%32 distinct for s<16

// c_k = 2*cos(2*pi*k/150), k = 4..21 (21 is a dummy pad slot, never used in results)
__device__ __constant__ float C2TAB[18] = {
  1.9719921f,  // k=4  (9.6 deg)
  1.9562952f,  // k=5  (12)
  1.9371663f,  // k=6  (14.4)
  1.9146390f,  // k=7  (16.8)
  1.8887527f,  // k=8  (19.2)
  1.8595530f,  // k=9  (21.6)
  1.8270909f,  // k=10 (24)
  1.7914235f,  // k=11 (26.4)
  1.7526134f,  // k=12 (28.8)
  1.7107286f,  // k=13 (31.2)
  1.6658425f,  // k=14 (33.6)
  1.6180340f,  // k=15 (36)
  1.5673869f,  // k=16 (38.4)
  1.5139901f,  // k=17 (40.8)
  1.4579372f,  // k=18 (43.2)
  1.3993267f,  // k=19 (45.6)
  1.3382612f,  // k=20 (48)
  1.2748480f   // k=21 (50.4) dummy
};

__device__ __forceinline__ void gload_lds(const float* g, float* l) {
  __builtin_amdgcn_global_load_lds(
      (const __attribute__((address_space(1))) void*)g,
      (__attribute__((address_space(3))) void*)l,
      4, 0, 0);
}

// ---------------- Kernel 1: per-row PSD partials ----------------
// 4096 blocks x 64 threads (1 wave per (b,m) row).
// lane: seg = t>>2 (16 segs), g = t&3 (bin groups 5/4/4/4 over 17 bins).
// ws[r*18+0] = sum over segs/bins of normalized psd^2
// ws[r*18+1+f] = column sum over segs of normalized psd[f]
__global__ __launch_bounds__(64) void psd_partials(const float* __restrict__ mo,
                                                   const int* __restrict__ offs,
                                                   float* __restrict__ ws) {
  __shared__ float tile[KSEG * SEG_STRIDE];  // 9856 B

  const int r = blockIdx.x;
  const int t = threadIdx.x;
  const int seg = t >> 2;
  const int g = t & 3;

  const int off = offs[r * KSEG + seg];      // own seg's offset (4-lane broadcast)
  const float* __restrict__ rowp = mo + (size_t)r * T_LEN;

  // stage the 16 segments (150 floats each) into packed LDS, direct-to-LDS
  #pragma unroll
  for (int s = 0; s < KSEG; ++s) {
    const int off_s = __shfl(off, s << 2, 64);
    const float* src = rowp + off_s;
    float* dst = &tile[s * SEG_STRIDE];
    gload_lds(src + t, dst);                       // [0,64)
    gload_lds(src + 64 + t, dst + 64);             // [64,128)
    if (t < DTLEN - 128) gload_lds(src + 128 + t, dst + 128);  // [128,150)
  }
  __syncthreads();

  // bin group: g0 -> bins 4..8 (5), g1 -> 9..12, g2 -> 13..16, g3 -> 17..20
  const int boff = (g == 0) ? 0 : (1 + 4 * g);     // table index of first bin
  float c[5], s1[5], s2[5];
  #pragma unroll
  for (int j = 0; j < 5; ++j) {
    c[j] = C2TAB[boff + j];
    s1[j] = 0.0f;
    s2[j] = 0.0f;
  }

  const float* __restrict__ x = &tile[seg * SEG_STRIDE];
  #pragma unroll 5
  for (int n = 0; n < DTLEN; n += 2) {
    float x0 = x[n];
    float x1 = x[n + 1];
    #pragma unroll
    for (int j = 0; j < 5; ++j) {
      s2[j] = fmaf(c[j], s1[j], x0 - s2[j]);
      s1[j] = fmaf(c[j], s2[j], x1 - s1[j]);
    }
  }

  float p[5];
  #pragma unroll
  for (int j = 0; j < 5; ++j)
    p[j] = fmaf(s1[j], s1[j], s2[j] * s2[j]) - c[j] * s1[j] * s2[j];
  if (g != 0) p[4] = 0.0f;   // 5th slot only real for group 0

  // per-seg band sum across this seg's 4 lanes
  float bs = p[0] + p[1] + p[2] + p[3] + p[4];
  bs += __shfl_xor(bs, 1, 64);
  bs += __shfl_xor(bs, 2, 64);
  const float inv = 1.0f / bs;
  #pragma unroll
  for (int j = 0; j < 5; ++j) p[j] *= inv;

  // total sum of squares (all segs, all bins)
  float ssq = p[0]*p[0] + p[1]*p[1] + p[2]*p[2] + p[3]*p[3] + p[4]*p[4];
  #pragma unroll
  for (int m = 1; m <= 32; m <<= 1) ssq += __shfl_xor(ssq, m, 64);

  // column sums across segs (lanes with equal g, stride 4)
  #pragma unroll
  for (int m = 4; m <= 32; m <<= 1) {
    #pragma unroll
    for (int j = 0; j < 5; ++j) p[j] += __shfl_xor(p[j], m, 64);
  }

  float* wsr = ws + r * 18;
  if (t == 0) wsr[0] = ssq;
  if (t < 4) {
    const int nb = (t == 0) ? 5 : 4;
    #pragma unroll
    for (int j = 0; j < 5; ++j)
      if (j < nb) wsr[1 + boff + j] = p[j];
  }
}

// ---------------- Kernel 2: final reduction (1 block) ----------------
__global__ __launch_bounds__(1024) void final_reduce(const float* __restrict__ ws,
                                                     float* __restrict__ out) {
  const int t = threadIdx.x;
  double accA[18], accB[18];
  #pragma unroll
  for (int i = 0; i < 18; ++i) { accA[i] = 0.0; accB[i] = 0.0; }

  #pragma unroll
  for (int h = 0; h < 2; ++h) {
    const float* p = ws + (t + 1024 * h) * 18;
    #pragma unroll
    for (int e = 0; e < 18; ++e) accA[e] += (double)p[e];
  }
  #pragma unroll
  for (int h = 2; h < 4; ++h) {
    const float* p = ws + (t + 1024 * h) * 18;
    #pragma unroll
    for (int e = 0; e < 18; ++e) accB[e] += (double)p[e];
  }

  #pragma unroll
  for (int off = 32; off >= 1; off >>= 1) {
    #pragma unroll
    for (int i = 0; i < 18; ++i) {
      accA[i] += __shfl_down(accA[i], off, 64);
      accB[i] += __shfl_down(accB[i], off, 64);
    }
  }

  __shared__ double wsum[16][36];
  const int wid = t >> 6, lane = t & 63;
  if (lane == 0) {
    #pragma unroll
    for (int i = 0; i < 18; ++i) { wsum[wid][i] = accA[i]; wsum[wid][18 + i] = accB[i]; }
  }
  __syncthreads();

  __shared__ double fin[36];
  if (t < 36) {
    double s = 0.0;
    #pragma unroll
    for (int w = 0; w < 16; ++w) s += wsum[w][t];
    fin[t] = s;
  }
  __syncthreads();

  if (t == 0) {
    double sumA2 = fin[0], sumB2 = fin[18];
    double dAA = 0.0, dBB = 0.0, dAB = 0.0;
    for (int f = 0; f < NBIN; ++f) {
      double ca = fin[1 + f], cb = fin[19 + f];
      dAA += ca * ca;
      dBB += cb * cb;
      dAB += ca * cb;
    }
    const double N = 32768.0, Fb = 17.0;
    double pAA = (2.0 * N * sumA2 - 2.0 * dAA) / Fb;
    double pBB = (2.0 * N * sumB2 - 2.0 * dBB) / Fb;
    double pAB = (N * sumA2 + N * sumB2 - 2.0 * dAB) / Fb;
    double selfa = pAA / (N * (N - 1.0));
    double selfb = pBB / (N * (N - 1.0));
    double res = 0.5 * (selfa + selfb) + pAB / (N * N);
    out[0] = (float)res;
  }
}

extern "C" void kernel_launch(void* const* d_in, const int* in_sizes, int n_in,
                              void* d_out, int out_size, void* d_ws, size_t ws_size,
                              hipStream_t stream) {
  const float* mo = (const float*)d_in[0];   // (2, 2048, 4096) f32
  const int* offs = (const int*)d_in[1];     // (2, 2048, 16) i32
  float* out = (float*)d_out;
  float* ws = (float*)d_ws;                  // 4096*18*4 = 294912 B used

  psd_partials<<<NROWS, 64, 0, stream>>>(mo, offs, ws);
  final_reduce<<<1, 1024, 0, stream>>>(ws, out);
}

// Round 4
// 21.521 us; speedup vs baseline: 2.3765x; 2.0278x over previous
//
#include <hip/hip_runtime.h>
#include <stdint.h>

// ContrastLoss: B=2, M=2048, T=4096, K=16, DT=150
// Band bins of rfft(150) kept: k = 4..20 (17 bins). Mean-subtract & /dt cancel.
// Per-segment Goertzel -> normalized PSD -> closed-form loss from moments.
// ws layout (f32, transposed): ws[e*4096 + r], e=0 -> per-row sum of psd^2,
// e=1..17 -> per-row column sums. fin (f64, 36): fin[2e+v] partial per video.

#define T_LEN 4096
#define KSEG 16
#define NROWS 4096      // B*M
#define DTLEN 150
#define NBIN 17
#define SEG_STRIDE 154  // floats; banks (154*s+n)%32 = (26s+n)%32 distinct for s<16

// c_k = 2*cos(2*pi*k/150), k = 4..21 (21 is a dummy pad slot, never used)
__device__ __constant__ float C2TAB[18] = {
  1.9719921f, 1.9562952f, 1.9371663f, 1.9146390f, 1.8887527f, 1.8595530f,
  1.8270909f, 1.7914235f, 1.7526134f, 1.7107286f, 1.6658425f, 1.6180340f,
  1.5673869f, 1.5139901f, 1.4579372f, 1.3993267f, 1.3382612f, 1.2748480f
};

__device__ __forceinline__ void gload_lds(const float* g, float* l) {
  __builtin_amdgcn_global_load_lds(
      (const __attribute__((address_space(1))) void*)g,
      (__attribute__((address_space(3))) void*)l,
      4, 0, 0);
}

// ---------------- Kernel 1: per-row PSD partials ----------------
// 4096 blocks x 64 threads (1 wave per (b,m) row).
// lane: seg = t>>2 (16 segs), g = t&3 (bin groups 5/4/4/4 over 17 bins).
__global__ __launch_bounds__(64) void psd_partials(const float* __restrict__ mo,
                                                   const int* __restrict__ offs,
                                                   float* __restrict__ ws) {
  __shared__ float tile[KSEG * SEG_STRIDE];  // 9856 B

  const int r = blockIdx.x;
  const int t = threadIdx.x;
  const int seg = t >> 2;
  const int g = t & 3;

  const int off = offs[r * KSEG + seg];      // own seg's offset (4-lane broadcast)
  const float* __restrict__ rowp = mo + (size_t)r * T_LEN;

  // stage the 16 segments (150 floats each) into packed LDS, direct-to-LDS
  #pragma unroll
  for (int s = 0; s < KSEG; ++s) {
    const int off_s = __shfl(off, s << 2, 64);
    const float* src = rowp + off_s;
    float* dst = &tile[s * SEG_STRIDE];
    gload_lds(src + t, dst);                       // [0,64)
    gload_lds(src + 64 + t, dst + 64);             // [64,128)
    if (t < DTLEN - 128) gload_lds(src + 128 + t, dst + 128);  // [128,150)
  }
  __syncthreads();

  // bin group: g0 -> bins 4..8 (5), g1 -> 9..12, g2 -> 13..16, g3 -> 17..20
  const int boff = (g == 0) ? 0 : (1 + 4 * g);     // table index of first bin
  float c[5], s1[5], s2[5];
  #pragma unroll
  for (int j = 0; j < 5; ++j) {
    c[j] = C2TAB[boff + j];
    s1[j] = 0.0f;
    s2[j] = 0.0f;
  }

  const float* __restrict__ x = &tile[seg * SEG_STRIDE];
  #pragma unroll 5
  for (int n = 0; n < DTLEN; n += 2) {
    float x0 = x[n];
    float x1 = x[n + 1];
    #pragma unroll
    for (int j = 0; j < 5; ++j) {
      s2[j] = fmaf(c[j], s1[j], x0 - s2[j]);
      s1[j] = fmaf(c[j], s2[j], x1 - s1[j]);
    }
  }

  float p[5];
  #pragma unroll
  for (int j = 0; j < 5; ++j)
    p[j] = fmaf(s1[j], s1[j], s2[j] * s2[j]) - c[j] * s1[j] * s2[j];
  if (g != 0) p[4] = 0.0f;   // 5th slot only real for group 0

  // per-seg band sum across this seg's 4 lanes
  float bs = p[0] + p[1] + p[2] + p[3] + p[4];
  bs += __shfl_xor(bs, 1, 64);
  bs += __shfl_xor(bs, 2, 64);
  const float inv = 1.0f / bs;
  #pragma unroll
  for (int j = 0; j < 5; ++j) p[j] *= inv;

  // total sum of squares (all segs, all bins)
  float ssq = p[0]*p[0] + p[1]*p[1] + p[2]*p[2] + p[3]*p[3] + p[4]*p[4];
  #pragma unroll
  for (int m = 1; m <= 32; m <<= 1) ssq += __shfl_xor(ssq, m, 64);

  // column sums across segs (lanes with equal g, stride 4)
  #pragma unroll
  for (int m = 4; m <= 32; m <<= 1) {
    #pragma unroll
    for (int j = 0; j < 5; ++j) p[j] += __shfl_xor(p[j], m, 64);
  }

  // transposed stores: e=0 plane gets ssq, e=1..17 get column sums
  if (t == 0) ws[r] = ssq;
  if (t < 4) {
    const int nb = (t == 0) ? 5 : 4;
    #pragma unroll
    for (int j = 0; j < 5; ++j)
      if (j < nb) ws[(1 + boff + j) * NROWS + r] = p[j];
  }
}

// ---------------- Kernel 2: coalesced column reduction ----------------
// 36 blocks: b -> (e = b>>1, v = b&1). Sums ws[e*4096 + v*2048 + 0..2047].
__global__ __launch_bounds__(256) void col_reduce(const float* __restrict__ ws,
                                                  double* __restrict__ fin) {
  const int b = blockIdx.x;
  const int e = b >> 1, v = b & 1;
  const int t = threadIdx.x;
  const float* __restrict__ p = ws + e * NROWS + v * 2048 + t;

  double a = 0.0;
  #pragma unroll
  for (int k = 0; k < 8; ++k) a += (double)p[256 * k];

  #pragma unroll
  for (int off = 32; off >= 1; off >>= 1) a += __shfl_down(a, off, 64);

  __shared__ double s[4];
  const int wid = t >> 6, lane = t & 63;
  if (lane == 0) s[wid] = a;
  __syncthreads();
  if (t == 0) fin[b] = s[0] + s[1] + s[2] + s[3];
}

// ---------------- Kernel 3: closed-form scalar ----------------
__global__ __launch_bounds__(64) void finalize(const double* __restrict__ fin,
                                               float* __restrict__ out) {
  if (threadIdx.x == 0) {
    double sumA2 = fin[0], sumB2 = fin[1];
    double dAA = 0.0, dBB = 0.0, dAB = 0.0;
    #pragma unroll
    for (int f = 0; f < NBIN; ++f) {
      double ca = fin[2 * (1 + f)];
      double cb = fin[2 * (1 + f) + 1];
      dAA += ca * ca;
      dBB += cb * cb;
      dAB += ca * cb;
    }
    const double N = 32768.0, Fb = 17.0;
    double pAA = (2.0 * N * sumA2 - 2.0 * dAA) / Fb;
    double pBB = (2.0 * N * sumB2 - 2.0 * dBB) / Fb;
    double pAB = (N * sumA2 + N * sumB2 - 2.0 * dAB) / Fb;
    double selfa = pAA / (N * (N - 1.0));
    double selfb = pBB / (N * (N - 1.0));
    out[0] = (float)(0.5 * (selfa + selfb) + pAB / (N * N));
  }
}

extern "C" void kernel_launch(void* const* d_in, const int* in_sizes, int n_in,
                              void* d_out, int out_size, void* d_ws, size_t ws_size,
                              hipStream_t stream) {
  const float* mo = (const float*)d_in[0];   // (2, 2048, 4096) f32
  const int* offs = (const int*)d_in[1];     // (2, 2048, 16) i32
  float* out = (float*)d_out;
  float* ws = (float*)d_ws;                  // 18*4096*4 = 294912 B
  double* fin = (double*)((char*)d_ws + 294912);  // 36 f64, 8B-aligned

  psd_partials<<<NROWS, 64, 0, stream>>>(mo, offs, ws);
  col_reduce<<<36, 256, 0, stream>>>(ws, fin);
  finalize<<<1, 64, 0, stream>>>(fin, out);
}